// Round 7
// baseline (1469.154 us; speedup 1.0000x reference)
//
#include <hip/hip_runtime.h>
#include <hip/hip_bf16.h>
#include <stdint.h>

#define GRIDN 48
#define F 2304
#define C 128
#define H 8
#define DH 16
#define NB 2          // batch (meshes)
#define WID 256
#define NLV 49        // BFS levels for GRID=48, anchor at (24,24)
#define SMH (H * 18)  // per-face static-softmax state: 8 heads x {m, l, acc[16]}

typedef __hip_bfloat16 bf16;

__device__ __forceinline__ float b2f(bf16 v) { return __bfloat162float(v); }

// ---------------------------------------------------------------- K0: dtype detect + BFS-ring perm + flag clear
__global__ void k_permdetect(const void* __restrict__ x, int* __restrict__ flag,
                             int* __restrict__ permIdx, int* __restrict__ lvflags) {
    __shared__ int cnt[NLV], start[NLV];
    __shared__ int bad;
    int t = threadIdx.x;
    if (t == 0) bad = 0;
    if (t < NLV) cnt[t] = 0;
    for (int i = t; i < 2 * NLV + 2; i += 256) lvflags[i] = 0;   // level flags + lvdone[2]
    __syncthreads();
    {   // dtype detect on first 2048 elements
        const bf16* xb = (const bf16*)x;
        int insane = 0;
        #pragma unroll
        for (int i = 0; i < 8; ++i) {
            float v = b2f(xb[t * 8 + i]);
            if (!(fabsf(v) < 1e10f)) insane = 1;
        }
        if (insane) atomicOr(&bad, 1);
    }
    for (int f = t; f < F; f += 256) {
        int d = abs(f / GRIDN - GRIDN / 2) + abs(f % GRIDN - GRIDN / 2);
        atomicAdd(&cnt[d], 1);
    }
    __syncthreads();
    if (t == 0) {
        int s = 0;
        for (int l = 0; l < NLV; ++l) { start[l] = s; s += cnt[l]; }
        *flag = bad;
    }
    __syncthreads();
    for (int f = t; f < F; f += 256) {
        int d = abs(f / GRIDN - GRIDN / 2) + abs(f % GRIDN - GRIDN / 2);
        permIdx[f] = atomicAdd(&start[d], 1);
    }
}

// ---------------------------------------------------------------- K0b: convert all weights/biases to fp32
struct WSeg { const void* src; int off; int cnt; };
struct WSegs { WSeg s[14]; };

__global__ void k_convert(WSegs segs, const int* __restrict__ flag,
                          float* __restrict__ dst, int total) {
    int i = blockIdx.x * blockDim.x + threadIdx.x;
    if (i >= total) return;
    bool f32 = (*flag != 0);
    #pragma unroll 1
    for (int j = 0; j < 14; ++j) {
        int off = segs.s[j].off, cnt = segs.s[j].cnt;
        if (i >= off && i < off + cnt) {
            int k = i - off;
            dst[i] = f32 ? ((const float*)segs.s[j].src)[k]
                         : b2f(((const bf16*)segs.s[j].src)[k]);
            return;
        }
    }
}

// ---------------------------------------------------------------- K0c: transposed weight copies for the epilogue
__global__ void k_wtrans(const float* __restrict__ Wk, const float* __restrict__ Wv,
                         const float* __restrict__ Wo, float* __restrict__ wT) {
    int m = blockIdx.y;
    const float* s = m == 0 ? Wk : (m == 1 ? Wv : Wo);
    int c = blockIdx.x;
    int k = threadIdx.x;
    wT[((size_t)m * C + c) * C + k] = s[k * C + c];
}

// ---------------------------------------------------------------- K1: x[B,C,F] -> cur[B,F,C] f32
__global__ void k_transpose_in(const void* __restrict__ x, const int* __restrict__ flag,
                               float* __restrict__ cur) {
    __shared__ float tile[32][33];
    bool f32 = (*flag != 0);
    int b = blockIdx.z;
    int f0 = blockIdx.x * 32, c0 = blockIdx.y * 32;
    int tx = threadIdx.x, ty = threadIdx.y;            // 32 x 8
    #pragma unroll
    for (int i = 0; i < 4; ++i) {
        int c = c0 + ty + i * 8;
        size_t idx = ((size_t)b * C + c) * F + f0 + tx;
        tile[ty + i * 8][tx] = f32 ? ((const float*)x)[idx] : b2f(((const bf16*)x)[idx]);
    }
    __syncthreads();
    #pragma unroll
    for (int i = 0; i < 4; ++i) {
        int f = f0 + ty + i * 8;
        cur[((size_t)b * F + f) * C + c0 + tx] = tile[tx][ty + i * 8];
    }
}

// ---------------------------------------------------------------- K2: init projections (2 rows/block)
__global__ __launch_bounds__(128) void k_proj_init(
        const float* __restrict__ cur, const int* __restrict__ permIdx,
        const float* __restrict__ Wq, const float* __restrict__ Wk, const float* __restrict__ Wv,
        float* __restrict__ qh, float* __restrict__ khT, float* __restrict__ vhT) {
    __shared__ float rows[2][C];
    int r0 = blockIdx.x * 2;
    int tid = threadIdx.x;  // 0..127 = output channel
    rows[0][tid] = cur[(size_t)r0 * C + tid];
    rows[1][tid] = cur[(size_t)(r0 + 1) * C + tid];
    __syncthreads();
    float aq0 = 0.f, aq1 = 0.f, ak0 = 0.f, ak1 = 0.f, av0 = 0.f, av1 = 0.f;
    for (int k = 0; k < C; ++k) {
        float wq = Wq[k * C + tid];
        float wk = Wk[k * C + tid];
        float wv = Wv[k * C + tid];
        float x0 = rows[0][k], x1 = rows[1][k];
        aq0 = fmaf(x0, wq, aq0); aq1 = fmaf(x1, wq, aq1);
        ak0 = fmaf(x0, wk, ak0); ak1 = fmaf(x1, wk, ak1);
        av0 = fmaf(x0, wv, av0); av1 = fmaf(x1, wv, av1);
    }
    const float scale = 0.25f;  // 1/sqrt(DH)
    #pragma unroll
    for (int r = 0; r < 2; ++r) {
        int grow = r0 + r;
        int mesh = grow / F, face = grow % F;
        int p = permIdx[face];
        qh[(size_t)grow * C + tid] = (r == 0 ? aq0 : aq1) * scale;
        khT[((size_t)mesh * C + tid) * F + p] = r == 0 ? ak0 : ak1;
        vhT[((size_t)mesh * C + tid) * F + p] = r == 0 ? av0 : av1;
    }
}

struct Rings { int v[NLV + 1]; };
struct Pairs { int v[NLV + 1]; };

// ---------------------------------------------------------------- K2c: static attention partials.
// (unchanged — runs on pristine khT/vhT, covers key columns [rs_lv, F) per query)
__global__ __launch_bounds__(256) void k_static(
        int Bd, Rings rings, Pairs pairs,
        const int* __restrict__ levels,
        const float* __restrict__ qh_all,
        const float* __restrict__ khT, const float* __restrict__ vhT,
        float* __restrict__ smS) {
    int bx = blockIdx.x;
    int mesh = bx & 1;
    int gp = bx >> 1;
    int lv = 0;
    while (gp >= pairs.v[lv + 1]) ++lv;
    int spair = gp - pairs.v[lv];
    int rs = rings.v[lv];
    int s0 = spair * 2, s1 = s0 + 1;
    int face0 = (s0 < Bd) ? levels[lv * Bd + s0] : F;
    int face1 = (s1 < Bd) ? levels[lv * Bd + s1] : F;
    bool a0 = (face0 >= 0 && face0 < F), a1 = (face1 >= 0 && face1 < F);
    if (!a0 && !a1) return;

    __shared__ float sQh[2][C];
    int tid = threadIdx.x;
    size_t row0 = ((size_t)mesh * F + face0) * C;
    size_t row1 = ((size_t)mesh * F + face1) * C;
    if (tid < C) sQh[0][tid] = a0 ? qh_all[row0 + tid] : 0.f;
    else { int c = tid - C; sQh[1][c] = a1 ? qh_all[row1 + c] : 0.f; }
    __syncthreads();

    int head = tid >> 5, sub = tid & 31;
    float q0[DH], q1[DH];
    #pragma unroll
    for (int d = 0; d < DH; ++d) { q0[d] = sQh[0][head * DH + d]; q1[d] = sQh[1][head * DH + d]; }

    const float* Kb = khT + ((size_t)mesh * C + head * DH) * F;
    const float* Vb = vhT + ((size_t)mesh * C + head * DH) * F;

    float m0 = -1e30f, l0 = 0.f, m1 = -1e30f, l1 = 0.f;
    float acc0[DH], acc1[DH];
    #pragma unroll
    for (int d = 0; d < DH; ++d) { acc0[d] = 0.f; acc1[d] = 0.f; }

    int base0 = rs & ~127;
    for (int base = base0; base < F; base += 128) {
        int p4 = base + 4 * sub;
        float sx0 = 0, sy0 = 0, sz0 = 0, sw0 = 0;
        float sx1 = 0, sy1 = 0, sz1 = 0, sw1 = 0;
        #pragma unroll
        for (int d = 0; d < DH; ++d) {
            float4 kk = *(const float4*)(Kb + d * F + p4);
            float a = q0[d], b = q1[d];
            sx0 = fmaf(a, kk.x, sx0); sy0 = fmaf(a, kk.y, sy0);
            sz0 = fmaf(a, kk.z, sz0); sw0 = fmaf(a, kk.w, sw0);
            sx1 = fmaf(b, kk.x, sx1); sy1 = fmaf(b, kk.y, sy1);
            sz1 = fmaf(b, kk.z, sz1); sw1 = fmaf(b, kk.w, sw1);
        }
        float g0 = 1.f, g1 = 1.f, g2 = 1.f, g3 = 1.f;
        if (base < rs) {
            g0 = (p4     >= rs) ? 1.f : 0.f; g1 = (p4 + 1 >= rs) ? 1.f : 0.f;
            g2 = (p4 + 2 >= rs) ? 1.f : 0.f; g3 = (p4 + 3 >= rs) ? 1.f : 0.f;
        }
        float mx0 = fmaxf(fmaxf(sx0, sy0), fmaxf(sz0, sw0));
        float mn0 = fmaxf(m0, mx0);
        float c0 = __expf(m0 - mn0);
        float px0 = __expf(sx0 - mn0) * g0, py0 = __expf(sy0 - mn0) * g1;
        float pz0 = __expf(sz0 - mn0) * g2, pw0 = __expf(sw0 - mn0) * g3;
        l0 = fmaf(l0, c0, px0 + py0 + pz0 + pw0);
        m0 = mn0;
        float mx1 = fmaxf(fmaxf(sx1, sy1), fmaxf(sz1, sw1));
        float mn1 = fmaxf(m1, mx1);
        float c1e = __expf(m1 - mn1);
        float px1 = __expf(sx1 - mn1) * g0, py1 = __expf(sy1 - mn1) * g1;
        float pz1 = __expf(sz1 - mn1) * g2, pw1 = __expf(sw1 - mn1) * g3;
        l1 = fmaf(l1, c1e, px1 + py1 + pz1 + pw1);
        m1 = mn1;
        #pragma unroll
        for (int d = 0; d < DH; ++d) {
            float4 vv = *(const float4*)(Vb + d * F + p4);
            float w0 = fmaf(px0, vv.x, fmaf(py0, vv.y, fmaf(pz0, vv.z, pw0 * vv.w)));
            float w1 = fmaf(px1, vv.x, fmaf(py1, vv.y, fmaf(pz1, vv.z, pw1 * vv.w)));
            acc0[d] = fmaf(acc0[d], c0, w0);
            acc1[d] = fmaf(acc1[d], c1e, w1);
        }
    }

    #pragma unroll
    for (int w = 16; w >= 1; w >>= 1) {
        float mo = __shfl_xor(m0, w), lo = __shfl_xor(l0, w);
        float mn = fmaxf(m0, mo);
        float ca = __expf(m0 - mn), cb = __expf(mo - mn);
        l0 = l0 * ca + lo * cb;
        #pragma unroll
        for (int d = 0; d < DH; ++d) {
            float ao = __shfl_xor(acc0[d], w);
            acc0[d] = acc0[d] * ca + ao * cb;
        }
        m0 = mn;
        mo = __shfl_xor(m1, w); lo = __shfl_xor(l1, w);
        mn = fmaxf(m1, mo);
        ca = __expf(m1 - mn); cb = __expf(mo - mn);
        l1 = l1 * ca + lo * cb;
        #pragma unroll
        for (int d = 0; d < DH; ++d) {
            float ao = __shfl_xor(acc1[d], w);
            acc1[d] = acc1[d] * ca + ao * cb;
        }
        m1 = mn;
    }
    if (sub == 0) {
        if (a0) {
            float* S = smS + (size_t)(mesh * F + face0) * SMH + head * 18;
            S[0] = m0; S[1] = l0;
            #pragma unroll
            for (int d = 0; d < DH; ++d) S[2 + d] = acc0[d];
        }
        if (a1) {
            float* S = smS + (size_t)(mesh * F + face1) * SMH + head * 18;
            S[0] = m1; S[1] = l1;
            #pragma unroll
            for (int d = 0; d < DH; ++d) S[2 + d] = acc1[d];
        }
    }
}

// ---------------------------------------------------------------- K3: ALL 49 levels in ONE launch.
// 2352 pair-blocks ordered by level. Columns are final once written; rings complete in order.
// Each block: bulk-folds all completed rings (lvdone, poll-free, contiguous), per-ring-polls the
// remainder, merges with static state, epilogue, atomically stages its K/V column into khT/vhT
// (relaxed agent atomics at the L3 coherence point — rounds 4-6 proven), bumps its level flag;
// the last producer of a level fetch_max's lvdone. Relies on ascending blockIdx dispatch
// (same assumption rounds 4-6 used within-launch); bounded spin guard prevents hangs.
__global__ __launch_bounds__(256, 4) void k_flood(
        int Bd, Rings rings, Pairs pairs,
        const int* __restrict__ levels, const int* __restrict__ permIdx,
        const float* __restrict__ qh_all, float* __restrict__ cur,
        float* __restrict__ khT, float* __restrict__ vhT,
        const float* __restrict__ smS,
        const float* __restrict__ WkT, const float* __restrict__ WvT,
        const float* __restrict__ WoT,
        int* __restrict__ lvflags, int* __restrict__ lvdone) {
    int bx = blockIdx.x;
    int mesh = bx & 1;
    int gp2 = bx >> 1;
    int lv = 0;
    while (gp2 >= pairs.v[lv + 1]) ++lv;
    int spair = gp2 - pairs.v[lv];

    int s0 = spair * 2, s1 = s0 + 1;
    int face0 = (s0 < Bd) ? levels[lv * Bd + s0] : F;
    int face1 = (s1 < Bd) ? levels[lv * Bd + s1] : F;
    bool a0 = (face0 >= 0 && face0 < F), a1 = (face1 >= 0 && face1 < F);

    __shared__ __attribute__((aligned(16))) float sQh[2][C], sQ[2][C], sRed[2][C], sNew2[2][C];
    __shared__ float sL[2][H];
    int tid = threadIdx.x;
    size_t row0 = ((size_t)mesh * F + face0) * C;
    size_t row1 = ((size_t)mesh * F + face1) * C;
    if (tid < C) {
        if (a0) { sQ[0][tid] = cur[row0 + tid]; sQh[0][tid] = qh_all[row0 + tid]; }
        else    { sQ[0][tid] = 0.f; sQh[0][tid] = 0.f; }
    } else {
        int c = tid - C;
        if (a1) { sQ[1][c] = cur[row1 + c]; sQh[1][c] = qh_all[row1 + c]; }
        else    { sQ[1][c] = 0.f; sQh[1][c] = 0.f; }
    }
    __syncthreads();

    int head = tid >> 5, sub = tid & 31;
    float q0[DH], q1[DH];
    #pragma unroll
    for (int d = 0; d < DH; ++d) { q0[d] = sQh[0][head * DH + d]; q1[d] = sQh[1][head * DH + d]; }

    float* Kb = khT + ((size_t)mesh * C + head * DH) * F;
    float* Vb = vhT + ((size_t)mesh * C + head * DH) * F;

    float m0 = -1e30f, l0 = 0.f, m1 = -1e30f, l1 = 0.f;
    float acc0[DH], acc1[DH];
    #pragma unroll
    for (int d = 0; d < DH; ++d) { acc0[d] = 0.f; acc1[d] = 0.f; }

    // ---- dynamic folds over final columns of rings 0..lv-1 (coalesced relaxed atomic loads)
    #define FOLD_COL(p)                                                                 \
    {                                                                                   \
        float kvv[DH], vv[DH];                                                          \
        _Pragma("unroll")                                                               \
        for (int d = 0; d < DH; ++d)                                                    \
            kvv[d] = __hip_atomic_load(Kb + (size_t)d * F + (p), __ATOMIC_RELAXED,      \
                                       __HIP_MEMORY_SCOPE_AGENT);                       \
        _Pragma("unroll")                                                               \
        for (int d = 0; d < DH; ++d)                                                    \
            vv[d] = __hip_atomic_load(Vb + (size_t)d * F + (p), __ATOMIC_RELAXED,       \
                                      __HIP_MEMORY_SCOPE_AGENT);                        \
        float s0v = 0.f, s1v = 0.f;                                                     \
        _Pragma("unroll")                                                               \
        for (int d = 0; d < DH; ++d) {                                                  \
            s0v = fmaf(q0[d], kvv[d], s0v);                                             \
            s1v = fmaf(q1[d], kvv[d], s1v);                                             \
        }                                                                               \
        float mn0_ = fmaxf(m0, s0v);                                                    \
        float c0_ = __expf(m0 - mn0_), pw0_ = __expf(s0v - mn0_);                       \
        l0 = l0 * c0_ + pw0_;                                                           \
        _Pragma("unroll")                                                               \
        for (int d = 0; d < DH; ++d) acc0[d] = fmaf(acc0[d], c0_, pw0_ * vv[d]);        \
        m0 = mn0_;                                                                      \
        float mn1_ = fmaxf(m1, s1v);                                                    \
        float c1_ = __expf(m1 - mn1_), pw1_ = __expf(s1v - mn1_);                       \
        l1 = l1 * c1_ + pw1_;                                                           \
        _Pragma("unroll")                                                               \
        for (int d = 0; d < DH; ++d) acc1[d] = fmaf(acc1[d], c1_, pw1_ * vv[d]);        \
        m1 = mn1_;                                                                      \
    }

    int ld = __hip_atomic_load(&lvdone[mesh], __ATOMIC_RELAXED, __HIP_MEMORY_SCOPE_AGENT);
    if (ld > lv) ld = lv;
    int bulkEnd = rings.v[ld];
    for (int p = sub; p < bulkEnd; p += 32) FOLD_COL(p);

    for (int gpi = ld; gpi < lv; ++gpi) {
        int need = pairs.v[gpi + 1] - pairs.v[gpi];
        int* fl = &lvflags[gpi * 2 + mesh];
        int guard = 0;
        while (__hip_atomic_load(fl, __ATOMIC_RELAXED, __HIP_MEMORY_SCOPE_AGENT) < need
               && guard < (1 << 22)) {
            __builtin_amdgcn_s_sleep(1);
            ++guard;
        }
        int frs = rings.v[gpi], fre = rings.v[gpi + 1];
        for (int p = frs + sub; p < fre; p += 32) FOLD_COL(p);
    }
    #undef FOLD_COL

    // ---- merge 32 per-lane states per head
    #pragma unroll
    for (int w = 16; w >= 1; w >>= 1) {
        float mo = __shfl_xor(m0, w), lo = __shfl_xor(l0, w);
        float mn = fmaxf(m0, mo);
        float ca = __expf(m0 - mn), cb = __expf(mo - mn);
        l0 = l0 * ca + lo * cb;
        #pragma unroll
        for (int d = 0; d < DH; ++d) {
            float ao = __shfl_xor(acc0[d], w);
            acc0[d] = acc0[d] * ca + ao * cb;
        }
        m0 = mn;
        mo = __shfl_xor(m1, w); lo = __shfl_xor(l1, w);
        mn = fmaxf(m1, mo);
        ca = __expf(m1 - mn); cb = __expf(mo - mn);
        l1 = l1 * ca + lo * cb;
        #pragma unroll
        for (int d = 0; d < DH; ++d) {
            float ao = __shfl_xor(acc1[d], w);
            acc1[d] = acc1[d] * ca + ao * cb;
        }
        m1 = mn;
    }
    if (sub == 0) {
        // merge with the precomputed static state over [rs_lv, F)
        {
            int fr = a0 ? face0 : 0;
            const float* S = smS + (size_t)(mesh * F + fr) * SMH + head * 18;
            float ms = S[0], ls = S[1];
            float mn = fmaxf(m0, ms);
            float ca = __expf(m0 - mn), cb = __expf(ms - mn);
            sL[0][head] = l0 * ca + ls * cb;
            #pragma unroll
            for (int d = 0; d < DH; ++d)
                sRed[0][head * DH + d] = fmaf(acc0[d], ca, S[2 + d] * cb);
        }
        {
            int fr = a1 ? face1 : 0;
            const float* S = smS + (size_t)(mesh * F + fr) * SMH + head * 18;
            float ms = S[0], ls = S[1];
            float mn = fmaxf(m1, ms);
            float ca = __expf(m1 - mn), cb = __expf(ms - mn);
            sL[1][head] = l1 * ca + ls * cb;
            #pragma unroll
            for (int d = 0; d < DH; ++d)
                sRed[1][head * DH + d] = fmaf(acc1[d], ca, S[2 + d] * cb);
        }
    }
    __syncthreads();
    if (tid < C) sRed[0][tid] = sRed[0][tid] / sL[0][tid >> 4];
    else { int c = tid - C; sRed[1][c] = sRed[1][c] / sL[1][c >> 4]; }
    __syncthreads();

    // ---- epilogue: out-proj + resid (both queries in parallel, transposed Wo)
    {
        int j = tid >> 7;              // which query this half handles
        int c = tid & 127;
        bool act = j == 0 ? a0 : a1;
        float o = 0.f;
        const float4* WoR = (const float4*)(WoT + (size_t)c * C);
        const float4* Rr  = (const float4*)(&sRed[j][0]);
        #pragma unroll
        for (int k4 = 0; k4 < C / 4; ++k4) {
            float4 w = WoR[k4];
            float4 r = Rr[k4];
            o = fmaf(r.x, w.x, o); o = fmaf(r.y, w.y, o);
            o = fmaf(r.z, w.z, o); o = fmaf(r.w, w.w, o);
        }
        float nv = sQ[j][c] + o;
        sNew2[j][c] = nv;
        if (act) cur[(j == 0 ? row0 : row1) + c] = nv;
    }
    __syncthreads();

    // ---- K/V column refresh: atomic staging into khT/vhT (skip for last level — no consumers)
    if (lv != NLV - 1) {
        #pragma unroll 1
        for (int j = 0; j < 2; ++j) {
            bool act = j == 0 ? a0 : a1;
            if (!act) continue;
            int facej = j == 0 ? face0 : face1;
            int p = permIdx[facej];
            int c = tid & 127;
            const float* WT = (tid < C) ? WkT : WvT;
            float a = 0.f;
            const float4* Wr = (const float4*)(WT + (size_t)c * C);
            const float4* Nr = (const float4*)(&sNew2[j][0]);
            #pragma unroll
            for (int k4 = 0; k4 < C / 4; ++k4) {
                float4 w = Wr[k4];
                float4 x = Nr[k4];
                a = fmaf(x.x, w.x, a); a = fmaf(x.y, w.y, a);
                a = fmaf(x.z, w.z, a); a = fmaf(x.w, w.w, a);
            }
            if (tid < C)
                __hip_atomic_store(khT + ((size_t)mesh * C + c) * F + p, a,
                                   __ATOMIC_RELAXED, __HIP_MEMORY_SCOPE_AGENT);
            else
                __hip_atomic_store(vhT + ((size_t)mesh * C + c) * F + p, a,
                                   __ATOMIC_RELAXED, __HIP_MEMORY_SCOPE_AGENT);
        }
        __syncthreads();                           // drains all waves' stores (vmcnt 0) before flag
        if (tid == 0) {
            int need = pairs.v[lv + 1] - pairs.v[lv];
            int old = __hip_atomic_fetch_add(&lvflags[lv * 2 + mesh], 1,
                                             __ATOMIC_RELAXED, __HIP_MEMORY_SCOPE_AGENT);
            if (old == need - 1)
                __hip_atomic_fetch_max(&lvdone[mesh], lv + 1,
                                       __ATOMIC_RELAXED, __HIP_MEMORY_SCOPE_AGENT);
        }
    }
}

// ---------------------------------------------------------------- K4: 5-layer MLP + sigmoid (2 rows/block)
__global__ __launch_bounds__(256) void k_mlp(
        const float* __restrict__ cur,
        const float* __restrict__ W1, const float* __restrict__ b1,
        const float* __restrict__ W2, const float* __restrict__ b2,
        const float* __restrict__ W3, const float* __restrict__ b3,
        const float* __restrict__ W4, const float* __restrict__ b4,
        const float* __restrict__ W5, const float* __restrict__ b5,
        float* __restrict__ out_scores) {
    __shared__ float sIn[2][C];
    __shared__ float sA[2][WID];
    __shared__ float sB[2][WID];
    int tid = threadIdx.x;                        // 0..255
    int r0 = blockIdx.x * 2;
    for (int i = tid; i < 2 * C; i += 256) sIn[i >> 7][i & 127] = cur[(size_t)r0 * C + i];
    __syncthreads();
    {
        float a0 = 0.f, a1 = 0.f;
        for (int k = 0; k < C; ++k) {
            float w = W1[k * WID + tid];
            a0 = fmaf(sIn[0][k], w, a0);
            a1 = fmaf(sIn[1][k], w, a1);
        }
        float bias = b1[tid];
        sA[0][tid] = fmaxf(a0 + bias, 0.f);
        sA[1][tid] = fmaxf(a1 + bias, 0.f);
    }
    __syncthreads();
    {
        float a0 = 0.f, a1 = 0.f;
        for (int k = 0; k < WID; ++k) {
            float w = W2[k * WID + tid];
            a0 = fmaf(sA[0][k], w, a0);
            a1 = fmaf(sA[1][k], w, a1);
        }
        float bias = b2[tid];
        sB[0][tid] = fmaxf(a0 + bias, 0.f);
        sB[1][tid] = fmaxf(a1 + bias, 0.f);
    }
    __syncthreads();
    {
        float a0 = 0.f, a1 = 0.f;
        for (int k = 0; k < WID; ++k) {
            float w = W3[k * WID + tid];
            a0 = fmaf(sB[0][k], w, a0);
            a1 = fmaf(sB[1][k], w, a1);
        }
        float bias = b3[tid];
        sA[0][tid] = fmaxf(a0 + bias, 0.f);
        sA[1][tid] = fmaxf(a1 + bias, 0.f);
    }
    __syncthreads();
    {
        float a0 = 0.f, a1 = 0.f;
        for (int k = 0; k < WID; ++k) {
            float w = W4[k * WID + tid];
            a0 = fmaf(sA[0][k], w, a0);
            a1 = fmaf(sA[1][k], w, a1);
        }
        float bias = b4[tid];
        sB[0][tid] = fmaxf(a0 + bias, 0.f);
        sB[1][tid] = fmaxf(a1 + bias, 0.f);
    }
    __syncthreads();
    if (tid < 2) {
        float a = b5[0];
        for (int k = 0; k < WID; ++k) a = fmaf(sB[tid][k], W5[k], a);
        out_scores[r0 + tid] = 1.f / (1.f + __expf(-a));
    }
}

// ---------------------------------------------------------------- K5: cur[B,F,C] f32 -> out0[B,C,F] f32
__global__ void k_transpose_out(const float* __restrict__ cur, float* __restrict__ out) {
    __shared__ float tile[32][33];
    int b = blockIdx.z;
    int f0 = blockIdx.x * 32, c0 = blockIdx.y * 32;
    int tx = threadIdx.x, ty = threadIdx.y;
    #pragma unroll
    for (int i = 0; i < 4; ++i) {
        int f = f0 + ty + i * 8;
        tile[ty + i * 8][tx] = cur[((size_t)b * F + f) * C + c0 + tx];
    }
    __syncthreads();
    #pragma unroll
    for (int i = 0; i < 4; ++i) {
        int c = c0 + ty + i * 8;
        out[((size_t)b * C + c) * F + f0 + tx] = tile[tx][ty + i * 8];
    }
}

// ----------------------------------------------------------------
extern "C" void kernel_launch(void* const* d_in, const int* in_sizes, int n_in,
                              void* d_out, int out_size, void* d_ws, size_t ws_size,
                              hipStream_t stream) {
    const int* levels = (const int*)d_in[15];
    int Bd = in_sizes[15] / NLV;                  // ring capacity per level

    const size_t n = (size_t)NB * F * C;          // 589824
    float* cur  = (float*)d_ws;
    float* qh   = cur + n;
    float* khT  = qh + n;
    float* vhT  = khT + n;
    float* wbuf = vhT + n;                        // fp32 weight copies, 296193 floats
    float* wT   = wbuf + 296196;                  // transposed WkT/WvT/WoT, 3*16384 floats (16B-aligned)
    int*   permIdx = (int*)(wT + 49152);
    int*   flag = permIdx + F;                    // 1 int (dtype flag)
    int*   lvflags = flag + 1;                    // 2*NLV ints (level-done flags)
    int*   lvdone = lvflags + 2 * NLV;            // 2 ints (per-mesh completed-level counter)
    float* smS  = (float*)(permIdx + 2408);       // static softmax state: NB*F*SMH floats

    const int oWq = 0,       oWk = 16384,  oWv = 32768,  oWo = 49152;
    const int oW1 = 65536,   oB1 = 98304;
    const int oW2 = 98560,   oB2 = 164096;
    const int oW3 = 164352,  oB3 = 229888;
    const int oW4 = 230144,  oB4 = 295680;
    const int oW5 = 295936,  oB5 = 296192;
    const int wtot = 296193;

    WSegs segs = {{
        { d_in[1],  oWq, 16384 }, { d_in[2],  oWk, 16384 },
        { d_in[3],  oWv, 16384 }, { d_in[4],  oWo, 16384 },
        { d_in[5],  oW1, 32768 }, { d_in[6],  oB1, 256 },
        { d_in[7],  oW2, 65536 }, { d_in[8],  oB2, 256 },
        { d_in[9],  oW3, 65536 }, { d_in[10], oB3, 256 },
        { d_in[11], oW4, 65536 }, { d_in[12], oB4, 256 },
        { d_in[13], oW5, 256 },   { d_in[14], oB5, 1 },
    }};

    // host-side ring prefix + pair prefix (pure function of GRIDN; matches k_permdetect)
    Rings rings;
    Pairs pairs;
    int totPairs = 0;
    {
        int cnt[NLV];
        for (int l = 0; l < NLV; ++l) cnt[l] = 0;
        for (int i = 0; i < GRIDN; ++i)
            for (int j = 0; j < GRIDN; ++j)
                cnt[(i < 24 ? 24 - i : i - 24) + (j < 24 ? 24 - j : j - 24)]++;
        rings.v[0] = 0;
        pairs.v[0] = 0;
        for (int l = 0; l < NLV; ++l) {
            rings.v[l + 1] = rings.v[l] + cnt[l];
            pairs.v[l + 1] = pairs.v[l] + (cnt[l] + 1) / 2;
        }
        totPairs = pairs.v[NLV];
    }

    float* out0 = (float*)d_out;                  // final.transpose(0,2,1): [B,C,F] fp32
    float* out1 = out0 + (size_t)NB * C * F;      // scores: [B,F,1] fp32

    k_permdetect<<<1, 256, 0, stream>>>(d_in[0], flag, permIdx, lvflags);
    k_convert<<<(wtot + 255) / 256, 256, 0, stream>>>(segs, flag, wbuf, wtot);
    k_wtrans<<<dim3(C, 3), C, 0, stream>>>(wbuf + oWk, wbuf + oWv, wbuf + oWo, wT);
    k_transpose_in<<<dim3(F / 32, C / 32, NB), dim3(32, 8), 0, stream>>>(d_in[0], flag, cur);
    k_proj_init<<<(NB * F) / 2, 128, 0, stream>>>(cur, permIdx, wbuf + oWq, wbuf + oWk, wbuf + oWv,
                                                  qh, khT, vhT);

    // static partials for ALL queries at once (khT/vhT still pristine here)
    k_static<<<2 * totPairs, 256, 0, stream>>>(Bd, rings, pairs, levels, qh, khT, vhT, smS);

    // ALL 49 levels in one launch (flag-chained, full-machine dynamic folding)
    k_flood<<<2 * totPairs, 256, 0, stream>>>(Bd, rings, pairs, levels, permIdx, qh, cur,
                                              khT, vhT, smS,
                                              wT, wT + 16384, wT + 32768,
                                              lvflags, lvdone);

    k_mlp<<<(NB * F) / 2, 256, 0, stream>>>(cur, wbuf + oW1, wbuf + oB1, wbuf + oW2, wbuf + oB2,
                                            wbuf + oW3, wbuf + oB3, wbuf + oW4, wbuf + oB4,
                                            wbuf + oW5, wbuf + oB5, out1);
    k_transpose_out<<<dim3(F / 32, C / 32, NB), dim3(32, 8), 0, stream>>>(cur, out0);
}

// Round 10
// 1271.289 us; speedup vs baseline: 1.1556x; 1.1556x over previous
//
#include <hip/hip_runtime.h>
#include <hip/hip_bf16.h>
#include <stdint.h>

#define GRIDN 48
#define F 2304
#define C 128
#define H 8
#define DH 16
#define NB 2          // batch (meshes)
#define WID 256
#define NLV 49        // BFS levels for GRID=48, anchor at (24,24)
#define SMH (H * 18)  // per-face static-softmax state: 8 heads x {m, l, acc[16]}
#define LVS 32        // ints per level in lvflags (64B per (lv,mesh): mesh offset 16)

typedef __hip_bfloat16 bf16;

__device__ __forceinline__ float b2f(bf16 v) { return __bfloat162float(v); }

// ---------------------------------------------------------------- K0: dtype detect + BFS-ring perm + flag clear
__global__ void k_permdetect(const void* __restrict__ x, int* __restrict__ flag,
                             int* __restrict__ permIdx, int* __restrict__ lvflags) {
    __shared__ int cnt[NLV], start[NLV];
    __shared__ int bad;
    int t = threadIdx.x;
    if (t == 0) bad = 0;
    if (t < NLV) cnt[t] = 0;
    for (int i = t; i < NLV * LVS + 32; i += 256) lvflags[i] = 0;   // flags + lvdone
    __syncthreads();
    {   // dtype detect on first 2048 elements
        const bf16* xb = (const bf16*)x;
        int insane = 0;
        #pragma unroll
        for (int i = 0; i < 8; ++i) {
            float v = b2f(xb[t * 8 + i]);
            if (!(fabsf(v) < 1e10f)) insane = 1;
        }
        if (insane) atomicOr(&bad, 1);
    }
    for (int f = t; f < F; f += 256) {
        int d = abs(f / GRIDN - GRIDN / 2) + abs(f % GRIDN - GRIDN / 2);
        atomicAdd(&cnt[d], 1);
    }
    __syncthreads();
    if (t == 0) {
        int s = 0;
        for (int l = 0; l < NLV; ++l) { start[l] = s; s += cnt[l]; }
        *flag = bad;
    }
    __syncthreads();
    for (int f = t; f < F; f += 256) {
        int d = abs(f / GRIDN - GRIDN / 2) + abs(f % GRIDN - GRIDN / 2);
        permIdx[f] = atomicAdd(&start[d], 1);
    }
}

// ---------------------------------------------------------------- K0b: convert all weights/biases to fp32
struct WSeg { const void* src; int off; int cnt; };
struct WSegs { WSeg s[14]; };

__global__ void k_convert(WSegs segs, const int* __restrict__ flag,
                          float* __restrict__ dst, int total) {
    int i = blockIdx.x * blockDim.x + threadIdx.x;
    if (i >= total) return;
    bool f32 = (*flag != 0);
    #pragma unroll 1
    for (int j = 0; j < 14; ++j) {
        int off = segs.s[j].off, cnt = segs.s[j].cnt;
        if (i >= off && i < off + cnt) {
            int k = i - off;
            dst[i] = f32 ? ((const float*)segs.s[j].src)[k]
                         : b2f(((const bf16*)segs.s[j].src)[k]);
            return;
        }
    }
}

// ---------------------------------------------------------------- K0c: transposed weight copies for the epilogue
__global__ void k_wtrans(const float* __restrict__ Wk, const float* __restrict__ Wv,
                         const float* __restrict__ Wo, float* __restrict__ wT) {
    int m = blockIdx.y;
    const float* s = m == 0 ? Wk : (m == 1 ? Wv : Wo);
    int c = blockIdx.x;
    int k = threadIdx.x;
    wT[((size_t)m * C + c) * C + k] = s[k * C + c];
}

// ---------------------------------------------------------------- K1: x[B,C,F] -> cur[B,F,C] f32
__global__ void k_transpose_in(const void* __restrict__ x, const int* __restrict__ flag,
                               float* __restrict__ cur) {
    __shared__ float tile[32][33];
    bool f32 = (*flag != 0);
    int b = blockIdx.z;
    int f0 = blockIdx.x * 32, c0 = blockIdx.y * 32;
    int tx = threadIdx.x, ty = threadIdx.y;            // 32 x 8
    #pragma unroll
    for (int i = 0; i < 4; ++i) {
        int c = c0 + ty + i * 8;
        size_t idx = ((size_t)b * C + c) * F + f0 + tx;
        tile[ty + i * 8][tx] = f32 ? ((const float*)x)[idx] : b2f(((const bf16*)x)[idx]);
    }
    __syncthreads();
    #pragma unroll
    for (int i = 0; i < 4; ++i) {
        int f = f0 + ty + i * 8;
        cur[((size_t)b * F + f) * C + c0 + tx] = tile[tx][ty + i * 8];
    }
}

// ---------------------------------------------------------------- K2: init projections (2 rows/block)
__global__ __launch_bounds__(128) void k_proj_init(
        const float* __restrict__ cur, const int* __restrict__ permIdx,
        const float* __restrict__ Wq, const float* __restrict__ Wk, const float* __restrict__ Wv,
        float* __restrict__ qh, float* __restrict__ khT, float* __restrict__ vhT) {
    __shared__ float rows[2][C];
    int r0 = blockIdx.x * 2;
    int tid = threadIdx.x;  // 0..127 = output channel
    rows[0][tid] = cur[(size_t)r0 * C + tid];
    rows[1][tid] = cur[(size_t)(r0 + 1) * C + tid];
    __syncthreads();
    float aq0 = 0.f, aq1 = 0.f, ak0 = 0.f, ak1 = 0.f, av0 = 0.f, av1 = 0.f;
    for (int k = 0; k < C; ++k) {
        float wq = Wq[k * C + tid];
        float wk = Wk[k * C + tid];
        float wv = Wv[k * C + tid];
        float x0 = rows[0][k], x1 = rows[1][k];
        aq0 = fmaf(x0, wq, aq0); aq1 = fmaf(x1, wq, aq1);
        ak0 = fmaf(x0, wk, ak0); ak1 = fmaf(x1, wk, ak1);
        av0 = fmaf(x0, wv, av0); av1 = fmaf(x1, wv, av1);
    }
    const float scale = 0.25f;  // 1/sqrt(DH)
    #pragma unroll
    for (int r = 0; r < 2; ++r) {
        int grow = r0 + r;
        int mesh = grow / F, face = grow % F;
        int p = permIdx[face];
        qh[(size_t)grow * C + tid] = (r == 0 ? aq0 : aq1) * scale;
        khT[((size_t)mesh * C + tid) * F + p] = r == 0 ? ak0 : ak1;
        vhT[((size_t)mesh * C + tid) * F + p] = r == 0 ? av0 : av1;
    }
}

struct Rings { int v[NLV + 1]; };
struct Pairs { int v[NLV + 1]; };

// ---------------------------------------------------------------- K2c: static attention partials.
// (unchanged — runs on pristine khT/vhT, covers key columns [rs_lv, F) per query)
__global__ __launch_bounds__(256) void k_static(
        int Bd, Rings rings, Pairs pairs,
        const int* __restrict__ levels,
        const float* __restrict__ qh_all,
        const float* __restrict__ khT, const float* __restrict__ vhT,
        float* __restrict__ smS) {
    int bx = blockIdx.x;
    int mesh = bx & 1;
    int gp = bx >> 1;
    int lv = 0;
    while (gp >= pairs.v[lv + 1]) ++lv;
    int spair = gp - pairs.v[lv];
    int rs = rings.v[lv];
    int s0 = spair * 2, s1 = s0 + 1;
    int face0 = (s0 < Bd) ? levels[lv * Bd + s0] : F;
    int face1 = (s1 < Bd) ? levels[lv * Bd + s1] : F;
    bool a0 = (face0 >= 0 && face0 < F), a1 = (face1 >= 0 && face1 < F);
    if (!a0 && !a1) return;

    __shared__ float sQh[2][C];
    int tid = threadIdx.x;
    size_t row0 = ((size_t)mesh * F + face0) * C;
    size_t row1 = ((size_t)mesh * F + face1) * C;
    if (tid < C) sQh[0][tid] = a0 ? qh_all[row0 + tid] : 0.f;
    else { int c = tid - C; sQh[1][c] = a1 ? qh_all[row1 + c] : 0.f; }
    __syncthreads();

    int head = tid >> 5, sub = tid & 31;
    float q0[DH], q1[DH];
    #pragma unroll
    for (int d = 0; d < DH; ++d) { q0[d] = sQh[0][head * DH + d]; q1[d] = sQh[1][head * DH + d]; }

    const float* Kb = khT + ((size_t)mesh * C + head * DH) * F;
    const float* Vb = vhT + ((size_t)mesh * C + head * DH) * F;

    float m0 = -1e30f, l0 = 0.f, m1 = -1e30f, l1 = 0.f;
    float acc0[DH], acc1[DH];
    #pragma unroll
    for (int d = 0; d < DH; ++d) { acc0[d] = 0.f; acc1[d] = 0.f; }

    int base0 = rs & ~127;
    for (int base = base0; base < F; base += 128) {
        int p4 = base + 4 * sub;
        float sx0 = 0, sy0 = 0, sz0 = 0, sw0 = 0;
        float sx1 = 0, sy1 = 0, sz1 = 0, sw1 = 0;
        #pragma unroll
        for (int d = 0; d < DH; ++d) {
            float4 kk = *(const float4*)(Kb + d * F + p4);
            float a = q0[d], b = q1[d];
            sx0 = fmaf(a, kk.x, sx0); sy0 = fmaf(a, kk.y, sy0);
            sz0 = fmaf(a, kk.z, sz0); sw0 = fmaf(a, kk.w, sw0);
            sx1 = fmaf(b, kk.x, sx1); sy1 = fmaf(b, kk.y, sy1);
            sz1 = fmaf(b, kk.z, sz1); sw1 = fmaf(b, kk.w, sw1);
        }
        float g0 = 1.f, g1 = 1.f, g2 = 1.f, g3 = 1.f;
        if (base < rs) {
            g0 = (p4     >= rs) ? 1.f : 0.f; g1 = (p4 + 1 >= rs) ? 1.f : 0.f;
            g2 = (p4 + 2 >= rs) ? 1.f : 0.f; g3 = (p4 + 3 >= rs) ? 1.f : 0.f;
        }
        float mx0 = fmaxf(fmaxf(sx0, sy0), fmaxf(sz0, sw0));
        float mn0 = fmaxf(m0, mx0);
        float c0 = __expf(m0 - mn0);
        float px0 = __expf(sx0 - mn0) * g0, py0 = __expf(sy0 - mn0) * g1;
        float pz0 = __expf(sz0 - mn0) * g2, pw0 = __expf(sw0 - mn0) * g3;
        l0 = fmaf(l0, c0, px0 + py0 + pz0 + pw0);
        m0 = mn0;
        float mx1 = fmaxf(fmaxf(sx1, sy1), fmaxf(sz1, sw1));
        float mn1 = fmaxf(m1, mx1);
        float c1e = __expf(m1 - mn1);
        float px1 = __expf(sx1 - mn1) * g0, py1 = __expf(sy1 - mn1) * g1;
        float pz1 = __expf(sz1 - mn1) * g2, pw1 = __expf(sw1 - mn1) * g3;
        l1 = fmaf(l1, c1e, px1 + py1 + pz1 + pw1);
        m1 = mn1;
        #pragma unroll
        for (int d = 0; d < DH; ++d) {
            float4 vv = *(const float4*)(Vb + d * F + p4);
            float w0 = fmaf(px0, vv.x, fmaf(py0, vv.y, fmaf(pz0, vv.z, pw0 * vv.w)));
            float w1 = fmaf(px1, vv.x, fmaf(py1, vv.y, fmaf(pz1, vv.z, pw1 * vv.w)));
            acc0[d] = fmaf(acc0[d], c0, w0);
            acc1[d] = fmaf(acc1[d], c1e, w1);
        }
    }

    #pragma unroll
    for (int w = 16; w >= 1; w >>= 1) {
        float mo = __shfl_xor(m0, w), lo = __shfl_xor(l0, w);
        float mn = fmaxf(m0, mo);
        float ca = __expf(m0 - mn), cb = __expf(mo - mn);
        l0 = l0 * ca + lo * cb;
        #pragma unroll
        for (int d = 0; d < DH; ++d) {
            float ao = __shfl_xor(acc0[d], w);
            acc0[d] = acc0[d] * ca + ao * cb;
        }
        m0 = mn;
        mo = __shfl_xor(m1, w); lo = __shfl_xor(l1, w);
        mn = fmaxf(m1, mo);
        ca = __expf(m1 - mn); cb = __expf(mo - mn);
        l1 = l1 * ca + lo * cb;
        #pragma unroll
        for (int d = 0; d < DH; ++d) {
            float ao = __shfl_xor(acc1[d], w);
            acc1[d] = acc1[d] * ca + ao * cb;
        }
        m1 = mn;
    }
    if (sub == 0) {
        if (a0) {
            float* S = smS + (size_t)(mesh * F + face0) * SMH + head * 18;
            S[0] = m0; S[1] = l0;
            #pragma unroll
            for (int d = 0; d < DH; ++d) S[2 + d] = acc0[d];
        }
        if (a1) {
            float* S = smS + (size_t)(mesh * F + face1) * SMH + head * 18;
            S[0] = m1; S[1] = l1;
            #pragma unroll
            for (int d = 0; d < DH; ++d) S[2 + d] = acc1[d];
        }
    }
}

// ---------------------------------------------------------------- K3: ALL 49 levels in ONE launch.
// Round-8 contention fixes, plus the round-8 bug fix: lvdone is read ONCE by tid 0 and
// broadcast through LDS (sLd) so the staged-fold loop trip count is block-uniform — the
// __syncthreads() inside that loop is only legal with a uniform trip count. (Round 8 read
// lvdone per-thread while producers were bumping it -> divergent barrier counts -> corruption.)
__global__ __launch_bounds__(256, 4) void k_flood(
        int Bd, Rings rings, Pairs pairs,
        const int* __restrict__ levels, const int* __restrict__ permIdx,
        const float* __restrict__ qh_all, float* __restrict__ cur,
        float* __restrict__ khT, float* __restrict__ vhT,
        const float* __restrict__ smS,
        const float* __restrict__ WkT, const float* __restrict__ WvT,
        const float* __restrict__ WoT,
        int* __restrict__ lvflags, int* __restrict__ lvdone) {
    int bx = blockIdx.x;
    int mesh = bx & 1;
    int gp2 = bx >> 1;
    int lv = 0;
    while (gp2 >= pairs.v[lv + 1]) ++lv;
    int spair = gp2 - pairs.v[lv];

    int s0 = spair * 2, s1 = s0 + 1;
    int face0 = (s0 < Bd) ? levels[lv * Bd + s0] : F;
    int face1 = (s1 < Bd) ? levels[lv * Bd + s1] : F;
    bool a0 = (face0 >= 0 && face0 < F), a1 = (face1 >= 0 && face1 < F);

    __shared__ __attribute__((aligned(16))) float sQh[2][C], sQ[2][C], sRed[2][C], sNew2[2][C];
    __shared__ float sL[2][H];
    __shared__ int sLd;
    int tid = threadIdx.x;
    size_t row0 = ((size_t)mesh * F + face0) * C;
    size_t row1 = ((size_t)mesh * F + face1) * C;
    if (tid < C) {
        if (a0) { sQ[0][tid] = cur[row0 + tid]; sQh[0][tid] = qh_all[row0 + tid]; }
        else    { sQ[0][tid] = 0.f; sQh[0][tid] = 0.f; }
    } else {
        int c = tid - C;
        if (a1) { sQ[1][c] = cur[row1 + c]; sQh[1][c] = qh_all[row1 + c]; }
        else    { sQ[1][c] = 0.f; sQh[1][c] = 0.f; }
    }
    if (tid == 0)
        sLd = __hip_atomic_load(&lvdone[mesh * 16], __ATOMIC_RELAXED, __HIP_MEMORY_SCOPE_AGENT);
    __syncthreads();

    int head = tid >> 5, sub = tid & 31;
    float q0[DH], q1[DH];
    #pragma unroll
    for (int d = 0; d < DH; ++d) { q0[d] = sQh[0][head * DH + d]; q1[d] = sQh[1][head * DH + d]; }

    float* Kb = khT + ((size_t)mesh * C + head * DH) * F;
    float* Vb = vhT + ((size_t)mesh * C + head * DH) * F;

    float m0 = -1e30f, l0 = 0.f, m1 = -1e30f, l1 = 0.f;
    float acc0[DH], acc1[DH];
    #pragma unroll
    for (int d = 0; d < DH; ++d) { acc0[d] = 0.f; acc1[d] = 0.f; }

    // ---- dynamic folds over final columns of rings 0..lv-1 (coalesced relaxed atomic loads)
    #define FOLD_COL(p)                                                                 \
    {                                                                                   \
        float kvv[DH], vv[DH];                                                          \
        _Pragma("unroll")                                                               \
        for (int d = 0; d < DH; ++d)                                                    \
            kvv[d] = __hip_atomic_load(Kb + (size_t)d * F + (p), __ATOMIC_RELAXED,      \
                                       __HIP_MEMORY_SCOPE_AGENT);                       \
        _Pragma("unroll")                                                               \
        for (int d = 0; d < DH; ++d)                                                    \
            vv[d] = __hip_atomic_load(Vb + (size_t)d * F + (p), __ATOMIC_RELAXED,       \
                                      __HIP_MEMORY_SCOPE_AGENT);                        \
        float s0v = 0.f, s1v = 0.f;                                                     \
        _Pragma("unroll")                                                               \
        for (int d = 0; d < DH; ++d) {                                                  \
            s0v = fmaf(q0[d], kvv[d], s0v);                                             \
            s1v = fmaf(q1[d], kvv[d], s1v);                                             \
        }                                                                               \
        float mn0_ = fmaxf(m0, s0v);                                                    \
        float c0_ = __expf(m0 - mn0_), pw0_ = __expf(s0v - mn0_);                       \
        l0 = l0 * c0_ + pw0_;                                                           \
        _Pragma("unroll")                                                               \
        for (int d = 0; d < DH; ++d) acc0[d] = fmaf(acc0[d], c0_, pw0_ * vv[d]);        \
        m0 = mn0_;                                                                      \
        float mn1_ = fmaxf(m1, s1v);                                                    \
        float c1_ = __expf(m1 - mn1_), pw1_ = __expf(s1v - mn1_);                       \
        l1 = l1 * c1_ + pw1_;                                                           \
        _Pragma("unroll")                                                               \
        for (int d = 0; d < DH; ++d) acc1[d] = fmaf(acc1[d], c1_, pw1_ * vv[d]);        \
        m1 = mn1_;                                                                      \
    }

    int ld = sLd;                         // block-uniform (broadcast via LDS)
    if (ld > lv) ld = lv;
    int bulkEnd = rings.v[ld];
    for (int p = sub; p < bulkEnd; p += 32) FOLD_COL(p);

    for (int gpi = ld; gpi < lv; ++gpi) {     // uniform trip count -> barrier inside is legal
        if (tid == 0) {
            int need = pairs.v[gpi + 1] - pairs.v[gpi];
            int* fl = &lvflags[gpi * LVS + mesh * 16];
            int guard = 0;
            while (__hip_atomic_load(fl, __ATOMIC_RELAXED, __HIP_MEMORY_SCOPE_AGENT) < need
                   && guard < (1 << 22)) {
                __builtin_amdgcn_s_sleep(2);
                ++guard;
            }
        }
        __syncthreads();                       // all threads released after flag observation
        int frs = rings.v[gpi], fre = rings.v[gpi + 1];
        for (int p = frs + sub; p < fre; p += 32) FOLD_COL(p);
    }
    #undef FOLD_COL

    // ---- merge 32 per-lane states per head
    #pragma unroll
    for (int w = 16; w >= 1; w >>= 1) {
        float mo = __shfl_xor(m0, w), lo = __shfl_xor(l0, w);
        float mn = fmaxf(m0, mo);
        float ca = __expf(m0 - mn), cb = __expf(mo - mn);
        l0 = l0 * ca + lo * cb;
        #pragma unroll
        for (int d = 0; d < DH; ++d) {
            float ao = __shfl_xor(acc0[d], w);
            acc0[d] = acc0[d] * ca + ao * cb;
        }
        m0 = mn;
        mo = __shfl_xor(m1, w); lo = __shfl_xor(l1, w);
        mn = fmaxf(m1, mo);
        ca = __expf(m1 - mn); cb = __expf(mo - mn);
        l1 = l1 * ca + lo * cb;
        #pragma unroll
        for (int d = 0; d < DH; ++d) {
            float ao = __shfl_xor(acc1[d], w);
            acc1[d] = acc1[d] * ca + ao * cb;
        }
        m1 = mn;
    }
    if (sub == 0) {
        // merge with the precomputed static state over [rs_lv, F)
        {
            int fr = a0 ? face0 : 0;
            const float* S = smS + (size_t)(mesh * F + fr) * SMH + head * 18;
            float ms = S[0], ls = S[1];
            float mn = fmaxf(m0, ms);
            float ca = __expf(m0 - mn), cb = __expf(ms - mn);
            sL[0][head] = l0 * ca + ls * cb;
            #pragma unroll
            for (int d = 0; d < DH; ++d)
                sRed[0][head * DH + d] = fmaf(acc0[d], ca, S[2 + d] * cb);
        }
        {
            int fr = a1 ? face1 : 0;
            const float* S = smS + (size_t)(mesh * F + fr) * SMH + head * 18;
            float ms = S[0], ls = S[1];
            float mn = fmaxf(m1, ms);
            float ca = __expf(m1 - mn), cb = __expf(ms - mn);
            sL[1][head] = l1 * ca + ls * cb;
            #pragma unroll
            for (int d = 0; d < DH; ++d)
                sRed[1][head * DH + d] = fmaf(acc1[d], ca, S[2 + d] * cb);
        }
    }
    __syncthreads();
    if (tid < C) sRed[0][tid] = sRed[0][tid] / sL[0][tid >> 4];
    else { int c = tid - C; sRed[1][c] = sRed[1][c] / sL[1][c >> 4]; }
    __syncthreads();

    // ---- epilogue: out-proj + resid (both queries in parallel, transposed Wo)
    {
        int j = tid >> 7;              // which query this half handles
        int c = tid & 127;
        bool act = j == 0 ? a0 : a1;
        float o = 0.f;
        const float4* WoR = (const float4*)(WoT + (size_t)c * C);
        const float4* Rr  = (const float4*)(&sRed[j][0]);
        #pragma unroll
        for (int k4 = 0; k4 < C / 4; ++k4) {
            float4 w = WoR[k4];
            float4 r = Rr[k4];
            o = fmaf(r.x, w.x, o); o = fmaf(r.y, w.y, o);
            o = fmaf(r.z, w.z, o); o = fmaf(r.w, w.w, o);
        }
        float nv = sQ[j][c] + o;
        sNew2[j][c] = nv;
        if (act) cur[(j == 0 ? row0 : row1) + c] = nv;
    }
    __syncthreads();

    // ---- K/V column refresh, single pass: j = tid>>7 (query), (tid>>6)&1 (K|V),
    //      (tid&63)*2 = channel pair. Atomic staging into khT/vhT (skip last level).
    if (lv != NLV - 1) {
        int j = tid >> 7;
        bool act = j == 0 ? a0 : a1;
        if (act) {
            int facej = j == 0 ? face0 : face1;
            int p = permIdx[facej];
            int isV = (tid >> 6) & 1;
            int c2 = (tid & 63) * 2;
            const float* WT = isV ? WvT : WkT;
            float aa = 0.f, ab = 0.f;
            const float4* Wa = (const float4*)(WT + (size_t)c2 * C);
            const float4* Wb = (const float4*)(WT + (size_t)(c2 + 1) * C);
            const float4* Nr = (const float4*)(&sNew2[j][0]);
            #pragma unroll
            for (int k4 = 0; k4 < C / 4; ++k4) {
                float4 x = Nr[k4];
                float4 wa = Wa[k4], wb = Wb[k4];
                aa = fmaf(x.x, wa.x, aa); aa = fmaf(x.y, wa.y, aa);
                aa = fmaf(x.z, wa.z, aa); aa = fmaf(x.w, wa.w, aa);
                ab = fmaf(x.x, wb.x, ab); ab = fmaf(x.y, wb.y, ab);
                ab = fmaf(x.z, wb.z, ab); ab = fmaf(x.w, wb.w, ab);
            }
            float* B = (isV ? vhT : khT) + (size_t)mesh * C * F + p;
            __hip_atomic_store(B + (size_t)c2 * F, aa,
                               __ATOMIC_RELAXED, __HIP_MEMORY_SCOPE_AGENT);
            __hip_atomic_store(B + (size_t)(c2 + 1) * F, ab,
                               __ATOMIC_RELAXED, __HIP_MEMORY_SCOPE_AGENT);
        }
        __syncthreads();                           // drains all waves' stores (vmcnt 0) before flag
        if (tid == 0) {
            int need = pairs.v[lv + 1] - pairs.v[lv];
            int old = __hip_atomic_fetch_add(&lvflags[lv * LVS + mesh * 16], 1,
                                             __ATOMIC_RELAXED, __HIP_MEMORY_SCOPE_AGENT);
            if (old == need - 1)
                __hip_atomic_fetch_max(&lvdone[mesh * 16], lv + 1,
                                       __ATOMIC_RELAXED, __HIP_MEMORY_SCOPE_AGENT);
        }
    }
}

// ---------------------------------------------------------------- K4: 5-layer MLP + sigmoid (2 rows/block)
__global__ __launch_bounds__(256) void k_mlp(
        const float* __restrict__ cur,
        const float* __restrict__ W1, const float* __restrict__ b1,
        const float* __restrict__ W2, const float* __restrict__ b2,
        const float* __restrict__ W3, const float* __restrict__ b3,
        const float* __restrict__ W4, const float* __restrict__ b4,
        const float* __restrict__ W5, const float* __restrict__ b5,
        float* __restrict__ out_scores) {
    __shared__ float sIn[2][C];
    __shared__ float sA[2][WID];
    __shared__ float sB[2][WID];
    int tid = threadIdx.x;                        // 0..255
    int r0 = blockIdx.x * 2;
    for (int i = tid; i < 2 * C; i += 256) sIn[i >> 7][i & 127] = cur[(size_t)r0 * C + i];
    __syncthreads();
    {
        float a0 = 0.f, a1 = 0.f;
        for (int k = 0; k < C; ++k) {
            float w = W1[k * WID + tid];
            a0 = fmaf(sIn[0][k], w, a0);
            a1 = fmaf(sIn[1][k], w, a1);
        }
        float bias = b1[tid];
        sA[0][tid] = fmaxf(a0 + bias, 0.f);
        sA[1][tid] = fmaxf(a1 + bias, 0.f);
    }
    __syncthreads();
    {
        float a0 = 0.f, a1 = 0.f;
        for (int k = 0; k < WID; ++k) {
            float w = W2[k * WID + tid];
            a0 = fmaf(sA[0][k], w, a0);
            a1 = fmaf(sA[1][k], w, a1);
        }
        float bias = b2[tid];
        sB[0][tid] = fmaxf(a0 + bias, 0.f);
        sB[1][tid] = fmaxf(a1 + bias, 0.f);
    }
    __syncthreads();
    {
        float a0 = 0.f, a1 = 0.f;
        for (int k = 0; k < WID; ++k) {
            float w = W3[k * WID + tid];
            a0 = fmaf(sB[0][k], w, a0);
            a1 = fmaf(sB[1][k], w, a1);
        }
        float bias = b3[tid];
        sA[0][tid] = fmaxf(a0 + bias, 0.f);
        sA[1][tid] = fmaxf(a1 + bias, 0.f);
    }
    __syncthreads();
    {
        float a0 = 0.f, a1 = 0.f;
        for (int k = 0; k < WID; ++k) {
            float w = W4[k * WID + tid];
            a0 = fmaf(sA[0][k], w, a0);
            a1 = fmaf(sA[1][k], w, a1);
        }
        float bias = b4[tid];
        sB[0][tid] = fmaxf(a0 + bias, 0.f);
        sB[1][tid] = fmaxf(a1 + bias, 0.f);
    }
    __syncthreads();
    if (tid < 2) {
        float a = b5[0];
        for (int k = 0; k < WID; ++k) a = fmaf(sB[tid][k], W5[k], a);
        out_scores[r0 + tid] = 1.f / (1.f + __expf(-a));
    }
}

// ---------------------------------------------------------------- K5: cur[B,F,C] f32 -> out0[B,C,F] f32
__global__ void k_transpose_out(const float* __restrict__ cur, float* __restrict__ out) {
    __shared__ float tile[32][33];
    int b = blockIdx.z;
    int f0 = blockIdx.x * 32, c0 = blockIdx.y * 32;
    int tx = threadIdx.x, ty = threadIdx.y;
    #pragma unroll
    for (int i = 0; i < 4; ++i) {
        int f = f0 + ty + i * 8;
        tile[ty + i * 8][tx] = cur[((size_t)b * F + f) * C + c0 + tx];
    }
    __syncthreads();
    #pragma unroll
    for (int i = 0; i < 4; ++i) {
        int c = c0 + ty + i * 8;
        out[((size_t)b * C + c) * F + f0 + tx] = tile[tx][ty + i * 8];
    }
}

// ----------------------------------------------------------------
extern "C" void kernel_launch(void* const* d_in, const int* in_sizes, int n_in,
                              void* d_out, int out_size, void* d_ws, size_t ws_size,
                              hipStream_t stream) {
    const int* levels = (const int*)d_in[15];
    int Bd = in_sizes[15] / NLV;                  // ring capacity per level

    const size_t n = (size_t)NB * F * C;          // 589824
    float* cur  = (float*)d_ws;
    float* qh   = cur + n;
    float* khT  = qh + n;
    float* vhT  = khT + n;
    float* wbuf = vhT + n;                        // fp32 weight copies, 296193 floats
    float* wT   = wbuf + 296196;                  // transposed WkT/WvT/WoT, 3*16384 floats (16B-aligned)
    int*   permIdx = (int*)(wT + 49152);
    int*   flag = permIdx + F;                    // 1 int (dtype flag)
    int*   lvflags = permIdx + 2320;              // NLV*LVS ints, one 64B line per (lv,mesh)
    int*   lvdone = lvflags + NLV * LVS;          // 2 counters, 64B apart (mesh*16)
    float* smS  = (float*)(permIdx + 4096);       // static softmax state: NB*F*SMH floats

    const int oWq = 0,       oWk = 16384,  oWv = 32768,  oWo = 49152;
    const int oW1 = 65536,   oB1 = 98304;
    const int oW2 = 98560,   oB2 = 164096;
    const int oW3 = 164352,  oB3 = 229888;
    const int oW4 = 230144,  oB4 = 295680;
    const int oW5 = 295936,  oB5 = 296192;
    const int wtot = 296193;

    WSegs segs = {{
        { d_in[1],  oWq, 16384 }, { d_in[2],  oWk, 16384 },
        { d_in[3],  oWv, 16384 }, { d_in[4],  oWo, 16384 },
        { d_in[5],  oW1, 32768 }, { d_in[6],  oB1, 256 },
        { d_in[7],  oW2, 65536 }, { d_in[8],  oB2, 256 },
        { d_in[9],  oW3, 65536 }, { d_in[10], oB3, 256 },
        { d_in[11], oW4, 65536 }, { d_in[12], oB4, 256 },
        { d_in[13], oW5, 256 },   { d_in[14], oB5, 1 },
    }};

    // host-side ring prefix + pair prefix (pure function of GRIDN; matches k_permdetect)
    Rings rings;
    Pairs pairs;
    int totPairs = 0;
    {
        int cnt[NLV];
        for (int l = 0; l < NLV; ++l) cnt[l] = 0;
        for (int i = 0; i < GRIDN; ++i)
            for (int j = 0; j < GRIDN; ++j)
                cnt[(i < 24 ? 24 - i : i - 24) + (j < 24 ? 24 - j : j - 24)]++;
        rings.v[0] = 0;
        pairs.v[0] = 0;
        for (int l = 0; l < NLV; ++l) {
            rings.v[l + 1] = rings.v[l] + cnt[l];
            pairs.v[l + 1] = pairs.v[l] + (cnt[l] + 1) / 2;
        }
        totPairs = pairs.v[NLV];
    }

    float* out0 = (float*)d_out;                  // final.transpose(0,2,1): [B,C,F] fp32
    float* out1 = out0 + (size_t)NB * C * F;      // scores: [B,F,1] fp32

    k_permdetect<<<1, 256, 0, stream>>>(d_in[0], flag, permIdx, lvflags);
    k_convert<<<(wtot + 255) / 256, 256, 0, stream>>>(segs, flag, wbuf, wtot);
    k_wtrans<<<dim3(C, 3), C, 0, stream>>>(wbuf + oWk, wbuf + oWv, wbuf + oWo, wT);
    k_transpose_in<<<dim3(F / 32, C / 32, NB), dim3(32, 8), 0, stream>>>(d_in[0], flag, cur);
    k_proj_init<<<(NB * F) / 2, 128, 0, stream>>>(cur, permIdx, wbuf + oWq, wbuf + oWk, wbuf + oWv,
                                                  qh, khT, vhT);

    // static partials for ALL queries at once (khT/vhT still pristine here)
    k_static<<<2 * totPairs, 256, 0, stream>>>(Bd, rings, pairs, levels, qh, khT, vhT, smS);

    // ALL 49 levels in one launch (flag-chained, full-machine dynamic folding)
    k_flood<<<2 * totPairs, 256, 0, stream>>>(Bd, rings, pairs, levels, permIdx, qh, cur,
                                              khT, vhT, smS,
                                              wT, wT + 16384, wT + 32768,
                                              lvflags, lvdone);

    k_mlp<<<(NB * F) / 2, 256, 0, stream>>>(cur, wbuf + oW1, wbuf + oB1, wbuf + oW2, wbuf + oB2,
                                            wbuf + oW3, wbuf + oB3, wbuf + oW4, wbuf + oB4,
                                            wbuf + oW5, wbuf + oB5, out1);
    k_transpose_out<<<dim3(F / 32, C / 32, NB), dim3(32, 8), 0, stream>>>(cur, out0);
}